// Round 7
// baseline (693.628 us; speedup 1.0000x reference)
//
#include <hip/hip_runtime.h>
#include <stdint.h>

// ---------------- types / helpers ----------------
typedef unsigned short bf16u;                                    // raw bf16 bits
typedef __attribute__((ext_vector_type(8))) __bf16 bf16x8;       // MFMA A/B frag
typedef __attribute__((ext_vector_type(4))) float f32x4;         // MFMA C/D frag
typedef __attribute__((ext_vector_type(4))) unsigned short u16x4;

typedef __attribute__((address_space(1))) void gvoid_t;
typedef __attribute__((address_space(3))) void lvoid_t;

#define SEQ 2048
#define DM 1024

__device__ __forceinline__ bf16u f2bf(float f) {
  union { float f; uint32_t u; } v; v.f = f;
  uint32_t u = v.u + 0x7fffu + ((v.u >> 16) & 1u);   // RNE (finite values only)
  return (bf16u)(u >> 16);
}

// async global->LDS, 16 bytes per lane. LDS dest must be wave-uniform base +
// lane*16 (no padding) — swizzle the GLOBAL source when a permuted LDS layout
// is wanted.
__device__ __forceinline__ void async_copy16(const bf16u* g, const bf16u* l) {
  __builtin_amdgcn_global_load_lds((gvoid_t*)(uintptr_t)g,
                                   (lvoid_t*)(uint32_t)(uintptr_t)l,
                                   16, 0, 0);
}

// ---------------- LayerNorm (fp32 in -> bf16 out) ----------------
__global__ __launch_bounds__(256) void ln_kernel(const float* __restrict__ x,
                                                 const float* __restrict__ g,
                                                 const float* __restrict__ be,
                                                 bf16u* __restrict__ out) {
  const int row = blockIdx.x;
  const int t = threadIdx.x;
  const float4 v = ((const float4*)(x + (size_t)row * DM))[t];
  float s  = v.x + v.y + v.z + v.w;
  float ss = v.x * v.x + v.y * v.y + v.z * v.z + v.w * v.w;
#pragma unroll
  for (int m = 1; m < 64; m <<= 1) {
    s  += __shfl_xor(s, m, 64);
    ss += __shfl_xor(ss, m, 64);
  }
  __shared__ float red[2][4];
  const int wv = t >> 6, ln = t & 63;
  if (ln == 0) { red[0][wv] = s; red[1][wv] = ss; }
  __syncthreads();
  s  = red[0][0] + red[0][1] + red[0][2] + red[0][3];
  ss = red[1][0] + red[1][1] + red[1][2] + red[1][3];
  const float mu = s * (1.0f / DM);
  const float var = ss * (1.0f / DM) - mu * mu;
  const float rstd = rsqrtf(var + 1e-5f);
  const float4 gg = ((const float4*)g)[t];
  const float4 bb = ((const float4*)be)[t];
  u16x4 o;
  o[0] = f2bf((v.x - mu) * rstd * gg.x + bb.x);
  o[1] = f2bf((v.y - mu) * rstd * gg.y + bb.y);
  o[2] = f2bf((v.z - mu) * rstd * gg.z + bb.z);
  o[3] = f2bf((v.w - mu) * rstd * gg.w + bb.w);
  *(u16x4*)(out + (size_t)row * DM + t * 4) = o;
}

// ---------------- weight transpose+cast: in (R x C) fp32 -> out (C x R) bf16 ----------------
__global__ __launch_bounds__(256) void wtrans(const float* __restrict__ in,
                                              bf16u* __restrict__ out, int R, int C) {
  __shared__ float tile[32][33];
  const int c0 = blockIdx.x * 32, r0 = blockIdx.y * 32;
  const int tx = threadIdx.x, ty = threadIdx.y;
#pragma unroll
  for (int i = 0; i < 4; ++i)
    tile[ty + i * 8][tx] = in[(size_t)(r0 + ty + i * 8) * C + c0 + tx];
  __syncthreads();
#pragma unroll
  for (int i = 0; i < 4; ++i)
    out[(size_t)(c0 + ty + i * 8) * R + r0 + tx] = f2bf(tile[tx][ty + i * 8]);
}

// batched version for the four 1024x1024 attention weights
__global__ __launch_bounds__(256) void wtrans4(const float* __restrict__ a,
                                               const float* __restrict__ b,
                                               const float* __restrict__ c,
                                               const float* __restrict__ d,
                                               bf16u* __restrict__ out) {
  const float* srcs[4] = {a, b, c, d};
  const float* in = srcs[blockIdx.z];
  bf16u* o = out + (size_t)blockIdx.z * 1024 * 1024;
  __shared__ float tile[32][33];
  const int c0 = blockIdx.x * 32, r0 = blockIdx.y * 32;
  const int tx = threadIdx.x, ty = threadIdx.y;
#pragma unroll
  for (int i = 0; i < 4; ++i)
    tile[ty + i * 8][tx] = in[(size_t)(r0 + ty + i * 8) * 1024 + c0 + tx];
  __syncthreads();
#pragma unroll
  for (int i = 0; i < 4; ++i)
    o[(size_t)(c0 + ty + i * 8) * 1024 + r0 + tx] = f2bf(tile[tx][ty + i * 8]);
}

// ---------------- V transpose: qkv v-section -> vt[bh][64][SEQ] bf16 ----------------
__global__ __launch_bounds__(256) void vtrans(const bf16u* __restrict__ qkv,
                                              bf16u* __restrict__ vt) {
  __shared__ bf16u tile[32][33];
  const int s0 = blockIdx.x * 32;
  const int d0 = blockIdx.y * 32;
  const int bh = blockIdx.z, b = bh >> 4, h = bh & 15;
  const int tx = threadIdx.x, ty = threadIdx.y;
#pragma unroll
  for (int i = 0; i < 4; ++i)
    tile[ty + i * 8][tx] =
        qkv[(size_t)(b * SEQ + s0 + ty + i * 8) * 3072 + 2048 + h * 64 + d0 + tx];
  __syncthreads();
#pragma unroll
  for (int i = 0; i < 4; ++i)
    vt[(size_t)(bh * 64 + d0 + ty + i * 8) * SEQ + s0 + tx] = tile[tx][ty + i * 8];
}

#define VM_WAIT(n) asm volatile("s_waitcnt vmcnt(" #n ")" ::: "memory")
#define BARRIER()  asm volatile("s_barrier" ::: "memory")

// ---------------- GEMM 128x128, BK=32, 3-stage ring pipelined K-loop --------
// Wait rule at the sub-iteration computing stage j: outstanding must drop to
// per_stage * (#stages staged after j) -> 8 / 4 / 0 (wave-uniform branches).
// mode 0: bf16 store | 1: +bias,relu,bf16 | 2: +resid fp32 | 3: +bias+resid fp32
__global__ __launch_bounds__(256, 3) void gemm_bt(
    const bf16u* __restrict__ A, const bf16u* __restrict__ Bt,
    int M, int N, int K,
    const float* __restrict__ bias, const float* __restrict__ resid,
    bf16u* __restrict__ outB, float* __restrict__ outF, int mode) {
  __shared__ bf16u As0[128 * 32], As1[128 * 32], As2[128 * 32];
  __shared__ bf16u Bs0[128 * 32], Bs1[128 * 32], Bs2[128 * 32];
  const int t = threadIdx.x;
  const int wv = t >> 6, ln = t & 63;
  const int col16 = ln & 15, quad = ln >> 4;
  const int wm = wv & 1, wn = wv >> 1;
  const int m0 = blockIdx.y * 128, n0 = blockIdx.x * 128;

  const int c0 = t, c1 = 256 + t;
  const bf16u* ga0 = A + (size_t)(m0 + (c0 >> 2)) * K + (c0 & 3) * 8;
  const bf16u* ga1 = A + (size_t)(m0 + (c1 >> 2)) * K + (c1 & 3) * 8;
  const bf16u* gb0 = Bt + (size_t)(n0 + (c0 >> 2)) * K + (c0 & 3) * 8;
  const bf16u* gb1 = Bt + (size_t)(n0 + (c1 >> 2)) * K + (c1 & 3) * 8;

  const int aoff = (wm * 64 + col16) * 32 + quad * 8;
  const int boff = (wn * 64 + col16) * 32 + quad * 8;

  f32x4 acc[4][4] = {};

  auto stage = [&](bf16u* dA, bf16u* dB) {
    async_copy16(ga0, dA + (size_t)c0 * 8);
    async_copy16(ga1, dA + (size_t)c1 * 8);
    async_copy16(gb0, dB + (size_t)c0 * 8);
    async_copy16(gb1, dB + (size_t)c1 * 8);
    ga0 += 32; ga1 += 32; gb0 += 32; gb1 += 32;
  };
  auto compute = [&](const bf16u* sA, const bf16u* sB) {
    bf16x8 af[4], bfv[4];
#pragma unroll
    for (int i = 0; i < 4; ++i) af[i] = *(const bf16x8*)(sA + aoff + i * 512);
#pragma unroll
    for (int i = 0; i < 4; ++i) bfv[i] = *(const bf16x8*)(sB + boff + i * 512);
#pragma unroll
    for (int mi = 0; mi < 4; ++mi)
#pragma unroll
      for (int ni = 0; ni < 4; ++ni)
        acc[mi][ni] = __builtin_amdgcn_mfma_f32_16x16x32_bf16(af[mi], bfv[ni],
                                                              acc[mi][ni], 0, 0, 0);
  };

  const int niter = K >> 5;     // >= 3 for all our shapes
  stage(As0, Bs0);
  stage(As1, Bs1);
  for (int k = 0; k < niter; k += 3) {
    if (k + 2 < niter) stage(As2, Bs2);
    if (k + 2 < niter) { VM_WAIT(8); } else if (k + 1 < niter) { VM_WAIT(4); } else { VM_WAIT(0); }
    BARRIER();
    compute(As0, Bs0);
    BARRIER();
    if (k + 1 >= niter) break;
    if (k + 3 < niter) stage(As0, Bs0);
    if (k + 3 < niter) { VM_WAIT(8); } else if (k + 2 < niter) { VM_WAIT(4); } else { VM_WAIT(0); }
    BARRIER();
    compute(As1, Bs1);
    BARRIER();
    if (k + 2 >= niter) break;
    if (k + 4 < niter) stage(As1, Bs1);
    if (k + 4 < niter) { VM_WAIT(8); } else if (k + 3 < niter) { VM_WAIT(4); } else { VM_WAIT(0); }
    BARRIER();
    compute(As2, Bs2);
    BARRIER();
  }

#pragma unroll
  for (int mi = 0; mi < 4; ++mi) {
#pragma unroll
    for (int ni = 0; ni < 4; ++ni) {
      const int col = n0 + wn * 64 + ni * 16 + col16;
#pragma unroll
      for (int r = 0; r < 4; ++r) {
        const int row = m0 + wm * 64 + mi * 16 + quad * 4 + r;
        float v = acc[mi][ni][r];
        if (mode == 1 || mode == 3) v += bias[col];
        if (mode == 1) v = fmaxf(v, 0.0f);
        if (mode >= 2) {
          outF[(size_t)row * N + col] = v + resid[(size_t)row * N + col];
        } else {
          outB[(size_t)row * N + col] = f2bf(v);
        }
      }
    }
  }
}

// ---------------- GEMM 64x128, BK=64, swizzled LDS, 3-stage ring ------------
// per_stage = 6 copies -> waits 12 / 6 / 0.
__global__ __launch_bounds__(256, 2) void gemm_bt64(
    const bf16u* __restrict__ A, const bf16u* __restrict__ Bt,
    int M, int N, int K,
    const float* __restrict__ bias, const float* __restrict__ resid,
    bf16u* __restrict__ outB, float* __restrict__ outF, int mode) {
  __shared__ bf16u As0[64 * 64], As1[64 * 64], As2[64 * 64];
  __shared__ bf16u Bs0[128 * 64], Bs1[128 * 64], Bs2[128 * 64];
  const int t = threadIdx.x;
  const int ln = t & 63;
  const int wv = t >> 6;
  const int col16 = ln & 15, quad = ln >> 4;
  const int m0 = blockIdx.y * 64, n0 = blockIdx.x * 128;

  // staging: rows of 64 elems = 8 slots of 8; slot XOR-swizzled by row&7
  const bf16u* gA[2];
  const bf16u* gB[4];
#pragma unroll
  for (int j = 0; j < 2; ++j) {
    const int c = t + 256 * j, row = c >> 3, slot = (c & 7) ^ (row & 7);
    gA[j] = A + (size_t)(m0 + row) * K + slot * 8;
  }
#pragma unroll
  for (int j = 0; j < 4; ++j) {
    const int c = t + 256 * j, row = c >> 3, slot = (c & 7) ^ (row & 7);
    gB[j] = Bt + (size_t)(n0 + row) * K + slot * 8;
  }

  f32x4 acc[4][2] = {};

  auto stage = [&](bf16u* dA, bf16u* dB) {
#pragma unroll
    for (int j = 0; j < 2; ++j) {
      async_copy16(gA[j], dA + (size_t)(t + 256 * j) * 8);
      gA[j] += 64;
    }
#pragma unroll
    for (int j = 0; j < 4; ++j) {
      async_copy16(gB[j], dB + (size_t)(t + 256 * j) * 8);
      gB[j] += 64;
    }
  };
  auto compute = [&](const bf16u* sA, const bf16u* sB) {
    bf16x8 af[4][2], bfv[2][2];
#pragma unroll
    for (int mi = 0; mi < 4; ++mi) {
      const int row = mi * 16 + col16;
#pragma unroll
      for (int kc = 0; kc < 2; ++kc)
        af[mi][kc] = *(const bf16x8*)(sA + row * 64 + (((kc << 2) + quad) ^ (row & 7)) * 8);
    }
#pragma unroll
    for (int ni = 0; ni < 2; ++ni) {
      const int row = wv * 32 + ni * 16 + col16;
#pragma unroll
      for (int kc = 0; kc < 2; ++kc)
        bfv[ni][kc] = *(const bf16x8*)(sB + row * 64 + (((kc << 2) + quad) ^ (row & 7)) * 8);
    }
#pragma unroll
    for (int kc = 0; kc < 2; ++kc)
#pragma unroll
      for (int mi = 0; mi < 4; ++mi)
#pragma unroll
        for (int ni = 0; ni < 2; ++ni)
          acc[mi][ni] = __builtin_amdgcn_mfma_f32_16x16x32_bf16(af[mi][kc], bfv[ni][kc],
                                                                acc[mi][ni], 0, 0, 0);
  };

  const int niter = K >> 6;     // 16 (wo) / 64 (ffn2)
  stage(As0, Bs0);
  stage(As1, Bs1);
  for (int k = 0; k < niter; k += 3) {
    if (k + 2 < niter) stage(As2, Bs2);
    if (k + 2 < niter) { VM_WAIT(12); } else if (k + 1 < niter) { VM_WAIT(6); } else { VM_WAIT(0); }
    BARRIER();
    compute(As0, Bs0);
    BARRIER();
    if (k + 1 >= niter) break;
    if (k + 3 < niter) stage(As0, Bs0);
    if (k + 3 < niter) { VM_WAIT(12); } else if (k + 2 < niter) { VM_WAIT(6); } else { VM_WAIT(0); }
    BARRIER();
    compute(As1, Bs1);
    BARRIER();
    if (k + 2 >= niter) break;
    if (k + 4 < niter) stage(As1, Bs1);
    if (k + 4 < niter) { VM_WAIT(12); } else if (k + 3 < niter) { VM_WAIT(6); } else { VM_WAIT(0); }
    BARRIER();
    compute(As2, Bs2);
    BARRIER();
  }

#pragma unroll
  for (int mi = 0; mi < 4; ++mi) {
#pragma unroll
    for (int ni = 0; ni < 2; ++ni) {
      const int col = n0 + wv * 32 + ni * 16 + col16;
#pragma unroll
      for (int r = 0; r < 4; ++r) {
        const int row = m0 + mi * 16 + quad * 4 + r;
        float v = acc[mi][ni][r];
        if (mode == 1 || mode == 3) v += bias[col];
        if (mode == 1) v = fmaxf(v, 0.0f);
        if (mode >= 2) {
          outF[(size_t)row * N + col] = v + resid[(size_t)row * N + col];
        } else {
          outB[(size_t)row * N + col] = f2bf(v);
        }
      }
    }
  }
}

// ---------------- causal flash attention v4 ----------------
// One 64-q-row strip per block, grid (bh=32, strips=32) heavy-first.
// No max-subtraction (scores are O(1) — exp2 range is safe by >20x margin):
// l accumulates per-lane, one 4-shuffle reduction per strip. No rescale.
// PV uses swapped MFMA operands -> O^T in C layout -> packed u16x4 stores.
#define PST 132   // pbuf row stride (elements): 128 keys + 4 pad
#define SCL 0.18033688f   // (1/8) * log2(e)
__global__ __launch_bounds__(256, 3) void attn_kernel(const bf16u* __restrict__ qkv,
                                                      const bf16u* __restrict__ vt,
                                                      bf16u* __restrict__ out) {
  __shared__ bf16u Ks[128 * 64];
  __shared__ bf16u Vts[2 * 64 * 64];
  __shared__ bf16u pbuf[4][16 * PST];
  __shared__ float lred[4][16];
  const int t = threadIdx.x;
  const int wv = t >> 6, ln = t & 63;
  const int col = ln & 15, quad = ln >> 4;
  const int bh = blockIdx.x, b = bh >> 4, h = bh & 15;
  const int strip = 31 - blockIdx.y;       // heavy blocks dispatch first
  const int q0 = strip * 64;
  const int qw = q0 + wv * 16;
  const int qmax = qw + 15;
  const int ntiles = (q0 >> 7) + 1;

  // staging constants: 1024 x 16B chunks per tile, 4 per thread
  int krow[4], kslot[4], vrow[4], vsub[4], vslot[4];
  const bf16u *kl[4], *vl[4];
#pragma unroll
  for (int j = 0; j < 4; ++j) {
    const int c = t + 256 * j;
    krow[j] = c >> 3; kslot[j] = (c & 7) ^ (krow[j] & 7);
    const int rem = c & 511;
    vsub[j] = c >> 9; vrow[j] = rem >> 3; vslot[j] = (rem & 7) ^ (vrow[j] & 7);
    kl[j] = Ks + (size_t)c * 8;
    vl[j] = Vts + (size_t)c * 8;
  }

  bf16x8 qf0, qf1;
  {
    const size_t qoff = (size_t)(b * SEQ + qw + col) * 3072 + h * 64 + quad * 8;
    qf0 = *(const bf16x8*)(qkv + qoff);
    qf1 = *(const bf16x8*)(qkv + qoff + 32);
  }
  f32x4 po[4] = {};          // O^T accum: po[n] rows hd=n*16+quad*4+r, col q
  float ll[4] = {};          // per-lane softmax denominator partials

  for (int kb = 0; kb < ntiles; ++kb) {
    const int kbase = kb * 128;
#pragma unroll
    for (int j = 0; j < 4; ++j) {
      async_copy16(qkv + (size_t)(b * SEQ + kbase + krow[j]) * 3072 + 1024 + h * 64 + kslot[j] * 8, kl[j]);
      async_copy16(vt + (size_t)(bh * 64 + vrow[j]) * SEQ + kbase + vsub[j] * 64 + vslot[j] * 8, vl[j]);
    }
    asm volatile("s_waitcnt vmcnt(0)" ::: "memory");
    __syncthreads();

    if (kb < ntiles - 1) {
      // ---------- fully-unmasked 128-key tile ----------
      f32x4 sc[8];
#pragma unroll
      for (int n = 0; n < 8; ++n) {
        const int kr = n * 16 + col;
        const bf16x8 k0 = *(const bf16x8*)(Ks + kr * 64 + (quad ^ (kr & 7)) * 8);
        const bf16x8 k1 = *(const bf16x8*)(Ks + kr * 64 + ((4 + quad) ^ (kr & 7)) * 8);
        f32x4 z = {};
        z = __builtin_amdgcn_mfma_f32_16x16x32_bf16(qf0, k0, z, 0, 0, 0);
        sc[n] = __builtin_amdgcn_mfma_f32_16x16x32_bf16(qf1, k1, z, 0, 0, 0);
      }
#pragma unroll
      for (int r = 0; r < 4; ++r) {
#pragma unroll
        for (int n = 0; n < 8; ++n) {
          const float e = exp2f(sc[n][r] * SCL);
          ll[r] += e;
          pbuf[wv][(quad * 4 + r) * PST + n * 16 + col] = f2bf(e);
        }
      }
    } else {
      // ---------- diagonal tile: mask + wave-uniform n-tile skip ----------
      f32x4 sc[8];
      bool act[8];
#pragma unroll
      for (int n = 0; n < 8; ++n) {
        act[n] = (kbase + n * 16) <= qmax;
        if (act[n]) {
          const int kr = n * 16 + col;
          const bf16x8 k0 = *(const bf16x8*)(Ks + kr * 64 + (quad ^ (kr & 7)) * 8);
          const bf16x8 k1 = *(const bf16x8*)(Ks + kr * 64 + ((4 + quad) ^ (kr & 7)) * 8);
          f32x4 z = {};
          z = __builtin_amdgcn_mfma_f32_16x16x32_bf16(qf0, k0, z, 0, 0, 0);
          sc[n] = __builtin_amdgcn_mfma_f32_16x16x32_bf16(qf1, k1, z, 0, 0, 0);
        }
      }
#pragma unroll
      for (int r = 0; r < 4; ++r) {
        const int q = qw + quad * 4 + r;
#pragma unroll
        for (int n = 0; n < 8; ++n) {
          float e = 0.0f;
          if (act[n]) {
            float v = sc[n][r] * SCL;
            v = (kbase + n * 16 + col <= q) ? v : -1e30f;   // exp2(-1e30) -> 0
            e = exp2f(v);
          }
          ll[r] += e;
          pbuf[wv][(quad * 4 + r) * PST + n * 16 + col] = f2bf(e);
        }
      }
    }
    asm volatile("s_waitcnt lgkmcnt(0)" ::: "memory");   // wave-local P ready
    bf16x8 pa[4];
#pragma unroll
    for (int kc = 0; kc < 4; ++kc)
      pa[kc] = *(const bf16x8*)(&pbuf[wv][col * PST + kc * 32 + quad * 8]);
    if (kb < ntiles - 1) {
#pragma unroll
      for (int n = 0; n < 4; ++n) {
        const int vr = n * 16 + col;
#pragma unroll
        for (int kc = 0; kc < 4; ++kc) {
          const bf16x8 vfr = *(const bf16x8*)(Vts + (kc >> 1) * 4096 + vr * 64 +
                                              (((kc & 1) * 4 + quad) ^ (vr & 7)) * 8);
          // swapped operands: C = V^T * P^T = O^T (col=q, row=hd)
          po[n] = __builtin_amdgcn_mfma_f32_16x16x32_bf16(vfr, pa[kc], po[n], 0, 0, 0);
        }
      }
    } else {
#pragma unroll
      for (int n = 0; n < 4; ++n) {
        const int vr = n * 16 + col;
#pragma unroll
        for (int kc = 0; kc < 4; ++kc)
          if (kbase + kc * 32 <= qmax) {
            const bf16x8 vfr = *(const bf16x8*)(Vts + (kc >> 1) * 4096 + vr * 64 +
                                                (((kc & 1) * 4 + quad) ^ (vr & 7)) * 8);
            po[n] = __builtin_amdgcn_mfma_f32_16x16x32_bf16(vfr, pa[kc], po[n], 0, 0, 0);
          }
      }
    }
    asm volatile("s_waitcnt lgkmcnt(0)" ::: "memory");
    __syncthreads();   // Ks/Vts reused next iteration
  }

  // reduce l across the 16 q-columns, broadcast via LDS, normalize, store O^T
#pragma unroll
  for (int m = 1; m < 16; m <<= 1)
#pragma unroll
    for (int r = 0; r < 4; ++r) ll[r] += __shfl_xor(ll[r], m, 64);
  if (col == 0) {
#pragma unroll
    for (int r = 0; r < 4; ++r) lred[wv][quad * 4 + r] = ll[r];
  }
  asm volatile("s_waitcnt lgkmcnt(0)" ::: "memory");
  const float inv = 1.0f / lred[wv][col];
#pragma unroll
  for (int n = 0; n < 4; ++n) {
    u16x4 o;
#pragma unroll
    for (int r = 0; r < 4; ++r) o[r] = f2bf(po[n][r] * inv);
    *(u16x4*)(out + (size_t)(b * SEQ + qw + col) * DM + h * 64 + n * 16 + quad * 4) = o;
  }
}

// ---------------- launch ----------------
extern "C" void kernel_launch(void* const* d_in, const int* in_sizes, int n_in,
                              void* d_out, int out_size, void* d_ws, size_t ws_size,
                              hipStream_t stream) {
  const float* x   = (const float*)d_in[0];
  const float* wq  = (const float*)d_in[1];
  const float* wk  = (const float*)d_in[2];
  const float* wvv = (const float*)d_in[3];
  const float* wo  = (const float*)d_in[4];
  const float* w1  = (const float*)d_in[5];
  const float* b1  = (const float*)d_in[6];
  const float* w2  = (const float*)d_in[7];
  const float* b2  = (const float*)d_in[8];
  const float* g1  = (const float*)d_in[9];
  const float* be1 = (const float*)d_in[10];
  const float* g2  = (const float*)d_in[11];
  const float* be2 = (const float*)d_in[12];
  float* out = (float*)d_out;

  char* ws = (char*)d_ws;
  bf16u* wqkv_t = (bf16u*)(ws);              //  0 ..  6 MB  (3072 x 1024)
  bf16u* wo_t   = (bf16u*)(ws +  6291456);   //  6 ..  8 MB  (1024 x 1024)
  bf16u* w1_t   = (bf16u*)(ws +  8388608);   //  8 .. 16 MB  (4096 x 1024)
  bf16u* w2_t   = (bf16u*)(ws + 16777216);   // 16 .. 24 MB  (1024 x 4096)
  bf16u* lnbuf  = (bf16u*)(ws + 25165824);   // 24 .. 32 MB  (4096 x 1024) also attn out
  bf16u* qkv    = (bf16u*)(ws + 33554432);   // 32 .. 56 MB  (4096 x 3072)
  bf16u* vtb    = (bf16u*)(ws + 58720256);   // 56 .. 64 MB  (32 x 64 x 2048)
  bf16u* h1     = (bf16u*)(ws + 33554432);   // 32 .. 64 MB  (reuse: 4096 x 4096)
  bf16u* attn   = lnbuf;                     // ln1 dead after QKV GEMM

  const dim3 tb32(32, 8);
  wtrans4<<<dim3(32, 32, 4), tb32, 0, stream>>>(wq, wk, wvv, wo, wqkv_t);
  wtrans<<<dim3(128, 32), tb32, 0, stream>>>(w1, w1_t, 1024, 4096);
  wtrans<<<dim3(32, 128), tb32, 0, stream>>>(w2, w2_t, 4096, 1024);

  ln_kernel<<<4096, 256, 0, stream>>>(x, g1, be1, lnbuf);
  gemm_bt<<<dim3(24, 32), 256, 0, stream>>>(lnbuf, wqkv_t, 4096, 3072, 1024,
                                            nullptr, nullptr, qkv, nullptr, 0);
  vtrans<<<dim3(64, 2, 32), tb32, 0, stream>>>(qkv, vtb);
  attn_kernel<<<dim3(32, 32), 256, 0, stream>>>(qkv, vtb, attn);
  gemm_bt64<<<dim3(8, 64), 256, 0, stream>>>(attn, wo_t, 4096, 1024, 1024,
                                             nullptr, x, nullptr, out, 2);
  ln_kernel<<<4096, 256, 0, stream>>>(out, g2, be2, lnbuf);
  gemm_bt<<<dim3(32, 32), 256, 0, stream>>>(lnbuf, w1_t, 4096, 4096, 1024,
                                            b1, nullptr, h1, nullptr, 1);
  gemm_bt64<<<dim3(8, 64), 256, 0, stream>>>(h1, w2_t, 4096, 1024, 4096,
                                             b2, out, nullptr, out, 3);
}

// Round 8
// 356.605 us; speedup vs baseline: 1.9451x; 1.9451x over previous
//
#include <hip/hip_runtime.h>
#include <stdint.h>

// ---------------- types / helpers ----------------
typedef unsigned short bf16u;                                    // raw bf16 bits
typedef __attribute__((ext_vector_type(8))) __bf16 bf16x8;       // MFMA A/B frag
typedef __attribute__((ext_vector_type(4))) float f32x4;         // MFMA C/D frag
typedef __attribute__((ext_vector_type(4))) unsigned short u16x4;

typedef __attribute__((address_space(1))) void gvoid_t;
typedef __attribute__((address_space(3))) void lvoid_t;

#define SEQ 2048
#define DM 1024

__device__ __forceinline__ bf16u f2bf(float f) {
  union { float f; uint32_t u; } v; v.f = f;
  uint32_t u = v.u + 0x7fffu + ((v.u >> 16) & 1u);   // RNE (finite values only)
  return (bf16u)(u >> 16);
}

// async global->LDS, 16 bytes per lane. LDS dest must be wave-uniform base +
// lane*16 (no padding) — swizzle the GLOBAL source when a permuted LDS layout
// is wanted.
__device__ __forceinline__ void async_copy16(const bf16u* g, const bf16u* l) {
  __builtin_amdgcn_global_load_lds((gvoid_t*)(uintptr_t)g,
                                   (lvoid_t*)(uint32_t)(uintptr_t)l,
                                   16, 0, 0);
}

// ---------------- LayerNorm (fp32 in -> bf16 out) ----------------
__global__ __launch_bounds__(256) void ln_kernel(const float* __restrict__ x,
                                                 const float* __restrict__ g,
                                                 const float* __restrict__ be,
                                                 bf16u* __restrict__ out) {
  const int row = blockIdx.x;
  const int t = threadIdx.x;
  const float4 v = ((const float4*)(x + (size_t)row * DM))[t];
  float s  = v.x + v.y + v.z + v.w;
  float ss = v.x * v.x + v.y * v.y + v.z * v.z + v.w * v.w;
#pragma unroll
  for (int m = 1; m < 64; m <<= 1) {
    s  += __shfl_xor(s, m, 64);
    ss += __shfl_xor(ss, m, 64);
  }
  __shared__ float red[2][4];
  const int wv = t >> 6, ln = t & 63;
  if (ln == 0) { red[0][wv] = s; red[1][wv] = ss; }
  __syncthreads();
  s  = red[0][0] + red[0][1] + red[0][2] + red[0][3];
  ss = red[1][0] + red[1][1] + red[1][2] + red[1][3];
  const float mu = s * (1.0f / DM);
  const float var = ss * (1.0f / DM) - mu * mu;
  const float rstd = rsqrtf(var + 1e-5f);
  const float4 gg = ((const float4*)g)[t];
  const float4 bb = ((const float4*)be)[t];
  u16x4 o;
  o[0] = f2bf((v.x - mu) * rstd * gg.x + bb.x);
  o[1] = f2bf((v.y - mu) * rstd * gg.y + bb.y);
  o[2] = f2bf((v.z - mu) * rstd * gg.z + bb.z);
  o[3] = f2bf((v.w - mu) * rstd * gg.w + bb.w);
  *(u16x4*)(out + (size_t)row * DM + t * 4) = o;
}

// ---------------- weight transpose+cast: in (R x C) fp32 -> out (C x R) bf16 ----------------
__global__ __launch_bounds__(256) void wtrans(const float* __restrict__ in,
                                              bf16u* __restrict__ out, int R, int C) {
  __shared__ float tile[32][33];
  const int c0 = blockIdx.x * 32, r0 = blockIdx.y * 32;
  const int tx = threadIdx.x, ty = threadIdx.y;
#pragma unroll
  for (int i = 0; i < 4; ++i)
    tile[ty + i * 8][tx] = in[(size_t)(r0 + ty + i * 8) * C + c0 + tx];
  __syncthreads();
#pragma unroll
  for (int i = 0; i < 4; ++i)
    out[(size_t)(c0 + ty + i * 8) * R + r0 + tx] = f2bf(tile[tx][ty + i * 8]);
}

// batched version for the four 1024x1024 attention weights
__global__ __launch_bounds__(256) void wtrans4(const float* __restrict__ a,
                                               const float* __restrict__ b,
                                               const float* __restrict__ c,
                                               const float* __restrict__ d,
                                               bf16u* __restrict__ out) {
  const float* srcs[4] = {a, b, c, d};
  const float* in = srcs[blockIdx.z];
  bf16u* o = out + (size_t)blockIdx.z * 1024 * 1024;
  __shared__ float tile[32][33];
  const int c0 = blockIdx.x * 32, r0 = blockIdx.y * 32;
  const int tx = threadIdx.x, ty = threadIdx.y;
#pragma unroll
  for (int i = 0; i < 4; ++i)
    tile[ty + i * 8][tx] = in[(size_t)(r0 + ty + i * 8) * 1024 + c0 + tx];
  __syncthreads();
#pragma unroll
  for (int i = 0; i < 4; ++i)
    o[(size_t)(c0 + ty + i * 8) * 1024 + r0 + tx] = f2bf(tile[tx][ty + i * 8]);
}

// ---------------- V transpose: qkv v-section -> vt[bh][64][SEQ] bf16 ----------------
__global__ __launch_bounds__(256) void vtrans(const bf16u* __restrict__ qkv,
                                              bf16u* __restrict__ vt) {
  __shared__ bf16u tile[32][33];
  const int s0 = blockIdx.x * 32;
  const int d0 = blockIdx.y * 32;
  const int bh = blockIdx.z, b = bh >> 4, h = bh & 15;
  const int tx = threadIdx.x, ty = threadIdx.y;
#pragma unroll
  for (int i = 0; i < 4; ++i)
    tile[ty + i * 8][tx] =
        qkv[(size_t)(b * SEQ + s0 + ty + i * 8) * 3072 + 2048 + h * 64 + d0 + tx];
  __syncthreads();
#pragma unroll
  for (int i = 0; i < 4; ++i)
    vt[(size_t)(bh * 64 + d0 + ty + i * 8) * SEQ + s0 + tx] = tile[tx][ty + i * 8];
}

#define VM_WAIT(n) asm volatile("s_waitcnt vmcnt(" #n ")" ::: "memory")
#define BARRIER()  asm volatile("s_barrier" ::: "memory")

// ---------------- GEMM 128x128, BK=32, 2-stage pipeline, swizzled LDS -------
// 32-elem rows = 4 slots of 8; slot XOR-swizzled by row&3 (4-way instead of
// 8-way bank aliasing on ds_read_b128). row&3 is invariant under +16 strides,
// so the frag read slot is per-lane constant.
// mode 0: bf16 store | 1: +bias,relu,bf16 | 2: +resid fp32 | 3: +bias+resid fp32
__global__ __launch_bounds__(256, 3) void gemm_bt(
    const bf16u* __restrict__ A, const bf16u* __restrict__ Bt,
    int M, int N, int K,
    const float* __restrict__ bias, const float* __restrict__ resid,
    bf16u* __restrict__ outB, float* __restrict__ outF, int mode) {
  __shared__ bf16u As0[128 * 32], As1[128 * 32];
  __shared__ bf16u Bs0[128 * 32], Bs1[128 * 32];
  const int t = threadIdx.x;
  const int wv = t >> 6, ln = t & 63;
  const int col16 = ln & 15, quad = ln >> 4;
  const int wm = wv & 1, wn = wv >> 1;
  const int m0 = blockIdx.y * 128, n0 = blockIdx.x * 128;

  // staging chunks c0=t, c1=256+t: row=c>>2, source slot=(c&3)^(row&3)
  const int c0 = t, c1 = 256 + t;
  const int r0c = c0 >> 2, r1c = c1 >> 2;
  const bf16u* ga0 = A + (size_t)(m0 + r0c) * K + (((c0 & 3) ^ (r0c & 3)) * 8);
  const bf16u* ga1 = A + (size_t)(m0 + r1c) * K + (((c1 & 3) ^ (r1c & 3)) * 8);
  const bf16u* gb0 = Bt + (size_t)(n0 + r0c) * K + (((c0 & 3) ^ (r0c & 3)) * 8);
  const bf16u* gb1 = Bt + (size_t)(n0 + r1c) * K + (((c1 & 3) ^ (r1c & 3)) * 8);

  const int rowa = wm * 64 + col16;
  const int rowb = wn * 64 + col16;
  const int aoff = rowa * 32 + (quad ^ (rowa & 3)) * 8;
  const int boff = rowb * 32 + (quad ^ (rowb & 3)) * 8;

  f32x4 acc[4][4] = {};

  auto stage = [&](bf16u* dA, bf16u* dB) {
    async_copy16(ga0, dA + (size_t)c0 * 8);
    async_copy16(ga1, dA + (size_t)c1 * 8);
    async_copy16(gb0, dB + (size_t)c0 * 8);
    async_copy16(gb1, dB + (size_t)c1 * 8);
    ga0 += 32; ga1 += 32; gb0 += 32; gb1 += 32;
  };
  auto compute = [&](const bf16u* sA, const bf16u* sB) {
    bf16x8 af[4], bfv[4];
#pragma unroll
    for (int i = 0; i < 4; ++i) af[i] = *(const bf16x8*)(sA + aoff + i * 512);
#pragma unroll
    for (int i = 0; i < 4; ++i) bfv[i] = *(const bf16x8*)(sB + boff + i * 512);
#pragma unroll
    for (int mi = 0; mi < 4; ++mi)
#pragma unroll
      for (int ni = 0; ni < 4; ++ni)
        acc[mi][ni] = __builtin_amdgcn_mfma_f32_16x16x32_bf16(af[mi], bfv[ni],
                                                              acc[mi][ni], 0, 0, 0);
  };

  const int niter = K >> 5;     // even for all our shapes (32)
  stage(As0, Bs0);
  for (int k = 0; k < niter; k += 2) {
    stage(As1, Bs1);            // k+1 always < niter (niter even)
    VM_WAIT(4);
    BARRIER();
    compute(As0, Bs0);
    BARRIER();
    if (k + 2 < niter) {
      stage(As0, Bs0);
      VM_WAIT(4);
    } else {
      VM_WAIT(0);
    }
    BARRIER();
    compute(As1, Bs1);
    BARRIER();
  }

#pragma unroll
  for (int mi = 0; mi < 4; ++mi) {
#pragma unroll
    for (int ni = 0; ni < 4; ++ni) {
      const int col = n0 + wn * 64 + ni * 16 + col16;
#pragma unroll
      for (int r = 0; r < 4; ++r) {
        const int row = m0 + wm * 64 + mi * 16 + quad * 4 + r;
        float v = acc[mi][ni][r];
        if (mode == 1 || mode == 3) v += bias[col];
        if (mode == 1) v = fmaxf(v, 0.0f);
        if (mode >= 2) {
          outF[(size_t)row * N + col] = v + resid[(size_t)row * N + col];
        } else {
          outB[(size_t)row * N + col] = f2bf(v);
        }
      }
    }
  }
}

// ---------------- GEMM 64x128, BK=64, swizzled LDS, 3-stage ring ------------
// per_stage = 6 copies -> waits 12 / 6 / 0 (tail-exact; verified round 7).
__global__ __launch_bounds__(256, 2) void gemm_bt64(
    const bf16u* __restrict__ A, const bf16u* __restrict__ Bt,
    int M, int N, int K,
    const float* __restrict__ bias, const float* __restrict__ resid,
    bf16u* __restrict__ outB, float* __restrict__ outF, int mode) {
  __shared__ bf16u As0[64 * 64], As1[64 * 64], As2[64 * 64];
  __shared__ bf16u Bs0[128 * 64], Bs1[128 * 64], Bs2[128 * 64];
  const int t = threadIdx.x;
  const int ln = t & 63;
  const int wv = t >> 6;
  const int col16 = ln & 15, quad = ln >> 4;
  const int m0 = blockIdx.y * 64, n0 = blockIdx.x * 128;

  // staging: rows of 64 elems = 8 slots of 8; slot XOR-swizzled by row&7
  const bf16u* gA[2];
  const bf16u* gB[4];
#pragma unroll
  for (int j = 0; j < 2; ++j) {
    const int c = t + 256 * j, row = c >> 3, slot = (c & 7) ^ (row & 7);
    gA[j] = A + (size_t)(m0 + row) * K + slot * 8;
  }
#pragma unroll
  for (int j = 0; j < 4; ++j) {
    const int c = t + 256 * j, row = c >> 3, slot = (c & 7) ^ (row & 7);
    gB[j] = Bt + (size_t)(n0 + row) * K + slot * 8;
  }

  f32x4 acc[4][2] = {};

  auto stage = [&](bf16u* dA, bf16u* dB) {
#pragma unroll
    for (int j = 0; j < 2; ++j) {
      async_copy16(gA[j], dA + (size_t)(t + 256 * j) * 8);
      gA[j] += 64;
    }
#pragma unroll
    for (int j = 0; j < 4; ++j) {
      async_copy16(gB[j], dB + (size_t)(t + 256 * j) * 8);
      gB[j] += 64;
    }
  };
  auto compute = [&](const bf16u* sA, const bf16u* sB) {
    bf16x8 af[4][2], bfv[2][2];
#pragma unroll
    for (int mi = 0; mi < 4; ++mi) {
      const int row = mi * 16 + col16;
#pragma unroll
      for (int kc = 0; kc < 2; ++kc)
        af[mi][kc] = *(const bf16x8*)(sA + row * 64 + (((kc << 2) + quad) ^ (row & 7)) * 8);
    }
#pragma unroll
    for (int ni = 0; ni < 2; ++ni) {
      const int row = wv * 32 + ni * 16 + col16;
#pragma unroll
      for (int kc = 0; kc < 2; ++kc)
        bfv[ni][kc] = *(const bf16x8*)(sB + row * 64 + (((kc << 2) + quad) ^ (row & 7)) * 8);
    }
#pragma unroll
    for (int kc = 0; kc < 2; ++kc)
#pragma unroll
      for (int mi = 0; mi < 4; ++mi)
#pragma unroll
        for (int ni = 0; ni < 2; ++ni)
          acc[mi][ni] = __builtin_amdgcn_mfma_f32_16x16x32_bf16(af[mi][kc], bfv[ni][kc],
                                                                acc[mi][ni], 0, 0, 0);
  };

  const int niter = K >> 6;     // 16 (wo) / 64 (ffn2)
  stage(As0, Bs0);
  stage(As1, Bs1);
  for (int k = 0; k < niter; k += 3) {
    if (k + 2 < niter) stage(As2, Bs2);
    if (k + 2 < niter) { VM_WAIT(12); } else if (k + 1 < niter) { VM_WAIT(6); } else { VM_WAIT(0); }
    BARRIER();
    compute(As0, Bs0);
    BARRIER();
    if (k + 1 >= niter) break;
    if (k + 3 < niter) stage(As0, Bs0);
    if (k + 3 < niter) { VM_WAIT(12); } else if (k + 2 < niter) { VM_WAIT(6); } else { VM_WAIT(0); }
    BARRIER();
    compute(As1, Bs1);
    BARRIER();
    if (k + 2 >= niter) break;
    if (k + 4 < niter) stage(As1, Bs1);
    if (k + 4 < niter) { VM_WAIT(12); } else if (k + 3 < niter) { VM_WAIT(6); } else { VM_WAIT(0); }
    BARRIER();
    compute(As2, Bs2);
    BARRIER();
  }

#pragma unroll
  for (int mi = 0; mi < 4; ++mi) {
#pragma unroll
    for (int ni = 0; ni < 2; ++ni) {
      const int col = n0 + wv * 32 + ni * 16 + col16;
#pragma unroll
      for (int r = 0; r < 4; ++r) {
        const int row = m0 + mi * 16 + quad * 4 + r;
        float v = acc[mi][ni][r];
        if (mode == 1 || mode == 3) v += bias[col];
        if (mode == 1) v = fmaxf(v, 0.0f);
        if (mode >= 2) {
          outF[(size_t)row * N + col] = v + resid[(size_t)row * N + col];
        } else {
          outB[(size_t)row * N + col] = f2bf(v);
        }
      }
    }
  }
}

// ---------------- causal flash attention v4 ----------------
// One 64-q-row strip per block, grid (bh=32, strips=32) heavy-first.
// No max-subtraction (scores are O(1) — exp2 range is safe by >20x margin):
// l accumulates per-lane, one 4-shuffle reduction per strip. No rescale.
// PV uses swapped MFMA operands -> O^T in C layout -> packed u16x4 stores.
#define PST 132   // pbuf row stride (elements): 128 keys + 4 pad
#define SCL 0.18033688f   // (1/8) * log2(e)
__global__ __launch_bounds__(256, 3) void attn_kernel(const bf16u* __restrict__ qkv,
                                                      const bf16u* __restrict__ vt,
                                                      bf16u* __restrict__ out) {
  __shared__ bf16u Ks[128 * 64];
  __shared__ bf16u Vts[2 * 64 * 64];
  __shared__ bf16u pbuf[4][16 * PST];
  __shared__ float lred[4][16];
  const int t = threadIdx.x;
  const int wv = t >> 6, ln = t & 63;
  const int col = ln & 15, quad = ln >> 4;
  const int bh = blockIdx.x, b = bh >> 4, h = bh & 15;
  const int strip = 31 - blockIdx.y;       // heavy blocks dispatch first
  const int q0 = strip * 64;
  const int qw = q0 + wv * 16;
  const int qmax = qw + 15;
  const int ntiles = (q0 >> 7) + 1;

  // staging constants: 1024 x 16B chunks per tile, 4 per thread
  int krow[4], kslot[4], vrow[4], vsub[4], vslot[4];
  const bf16u *kl[4], *vl[4];
#pragma unroll
  for (int j = 0; j < 4; ++j) {
    const int c = t + 256 * j;
    krow[j] = c >> 3; kslot[j] = (c & 7) ^ (krow[j] & 7);
    const int rem = c & 511;
    vsub[j] = c >> 9; vrow[j] = rem >> 3; vslot[j] = (rem & 7) ^ (vrow[j] & 7);
    kl[j] = Ks + (size_t)c * 8;
    vl[j] = Vts + (size_t)c * 8;
  }

  bf16x8 qf0, qf1;
  {
    const size_t qoff = (size_t)(b * SEQ + qw + col) * 3072 + h * 64 + quad * 8;
    qf0 = *(const bf16x8*)(qkv + qoff);
    qf1 = *(const bf16x8*)(qkv + qoff + 32);
  }
  f32x4 po[4] = {};          // O^T accum: po[n] rows hd=n*16+quad*4+r, col q
  float ll[4] = {};          // per-lane softmax denominator partials

  for (int kb = 0; kb < ntiles; ++kb) {
    const int kbase = kb * 128;
#pragma unroll
    for (int j = 0; j < 4; ++j) {
      async_copy16(qkv + (size_t)(b * SEQ + kbase + krow[j]) * 3072 + 1024 + h * 64 + kslot[j] * 8, kl[j]);
      async_copy16(vt + (size_t)(bh * 64 + vrow[j]) * SEQ + kbase + vsub[j] * 64 + vslot[j] * 8, vl[j]);
    }
    asm volatile("s_waitcnt vmcnt(0)" ::: "memory");
    __syncthreads();

    if (kb < ntiles - 1) {
      // ---------- fully-unmasked 128-key tile ----------
      f32x4 sc[8];
#pragma unroll
      for (int n = 0; n < 8; ++n) {
        const int kr = n * 16 + col;
        const bf16x8 k0 = *(const bf16x8*)(Ks + kr * 64 + (quad ^ (kr & 7)) * 8);
        const bf16x8 k1 = *(const bf16x8*)(Ks + kr * 64 + ((4 + quad) ^ (kr & 7)) * 8);
        f32x4 z = {};
        z = __builtin_amdgcn_mfma_f32_16x16x32_bf16(qf0, k0, z, 0, 0, 0);
        sc[n] = __builtin_amdgcn_mfma_f32_16x16x32_bf16(qf1, k1, z, 0, 0, 0);
      }
#pragma unroll
      for (int r = 0; r < 4; ++r) {
#pragma unroll
        for (int n = 0; n < 8; ++n) {
          const float e = exp2f(sc[n][r] * SCL);
          ll[r] += e;
          pbuf[wv][(quad * 4 + r) * PST + n * 16 + col] = f2bf(e);
        }
      }
    } else {
      // ---------- diagonal tile: mask + wave-uniform n-tile skip ----------
      f32x4 sc[8];
      bool act[8];
#pragma unroll
      for (int n = 0; n < 8; ++n) {
        act[n] = (kbase + n * 16) <= qmax;
        if (act[n]) {
          const int kr = n * 16 + col;
          const bf16x8 k0 = *(const bf16x8*)(Ks + kr * 64 + (quad ^ (kr & 7)) * 8);
          const bf16x8 k1 = *(const bf16x8*)(Ks + kr * 64 + ((4 + quad) ^ (kr & 7)) * 8);
          f32x4 z = {};
          z = __builtin_amdgcn_mfma_f32_16x16x32_bf16(qf0, k0, z, 0, 0, 0);
          sc[n] = __builtin_amdgcn_mfma_f32_16x16x32_bf16(qf1, k1, z, 0, 0, 0);
        }
      }
#pragma unroll
      for (int r = 0; r < 4; ++r) {
        const int q = qw + quad * 4 + r;
#pragma unroll
        for (int n = 0; n < 8; ++n) {
          float e = 0.0f;
          if (act[n]) {
            float v = sc[n][r] * SCL;
            v = (kbase + n * 16 + col <= q) ? v : -1e30f;   // exp2(-1e30) -> 0
            e = exp2f(v);
          }
          ll[r] += e;
          pbuf[wv][(quad * 4 + r) * PST + n * 16 + col] = f2bf(e);
        }
      }
    }
    asm volatile("s_waitcnt lgkmcnt(0)" ::: "memory");   // wave-local P ready
    bf16x8 pa[4];
#pragma unroll
    for (int kc = 0; kc < 4; ++kc)
      pa[kc] = *(const bf16x8*)(&pbuf[wv][col * PST + kc * 32 + quad * 8]);
    if (kb < ntiles - 1) {
#pragma unroll
      for (int n = 0; n < 4; ++n) {
        const int vr = n * 16 + col;
#pragma unroll
        for (int kc = 0; kc < 4; ++kc) {
          const bf16x8 vfr = *(const bf16x8*)(Vts + (kc >> 1) * 4096 + vr * 64 +
                                              (((kc & 1) * 4 + quad) ^ (vr & 7)) * 8);
          // swapped operands: C = V^T * P^T = O^T (col=q, row=hd)
          po[n] = __builtin_amdgcn_mfma_f32_16x16x32_bf16(vfr, pa[kc], po[n], 0, 0, 0);
        }
      }
    } else {
#pragma unroll
      for (int n = 0; n < 4; ++n) {
        const int vr = n * 16 + col;
#pragma unroll
        for (int kc = 0; kc < 4; ++kc)
          if (kbase + kc * 32 <= qmax) {
            const bf16x8 vfr = *(const bf16x8*)(Vts + (kc >> 1) * 4096 + vr * 64 +
                                                (((kc & 1) * 4 + quad) ^ (vr & 7)) * 8);
            po[n] = __builtin_amdgcn_mfma_f32_16x16x32_bf16(vfr, pa[kc], po[n], 0, 0, 0);
          }
      }
    }
    asm volatile("s_waitcnt lgkmcnt(0)" ::: "memory");
    __syncthreads();   // Ks/Vts reused next iteration
  }

  // reduce l across the 16 q-columns, broadcast via LDS, normalize, store O^T
#pragma unroll
  for (int m = 1; m < 16; m <<= 1)
#pragma unroll
    for (int r = 0; r < 4; ++r) ll[r] += __shfl_xor(ll[r], m, 64);
  if (col == 0) {
#pragma unroll
    for (int r = 0; r < 4; ++r) lred[wv][quad * 4 + r] = ll[r];
  }
  asm volatile("s_waitcnt lgkmcnt(0)" ::: "memory");
  const float inv = 1.0f / lred[wv][col];
#pragma unroll
  for (int n = 0; n < 4; ++n) {
    u16x4 o;
#pragma unroll
    for (int r = 0; r < 4; ++r) o[r] = f2bf(po[n][r] * inv);
    *(u16x4*)(out + (size_t)(b * SEQ + qw + col) * DM + h * 64 + n * 16 + quad * 4) = o;
  }
}

// ---------------- launch ----------------
extern "C" void kernel_launch(void* const* d_in, const int* in_sizes, int n_in,
                              void* d_out, int out_size, void* d_ws, size_t ws_size,
                              hipStream_t stream) {
  const float* x   = (const float*)d_in[0];
  const float* wq  = (const float*)d_in[1];
  const float* wk  = (const float*)d_in[2];
  const float* wvv = (const float*)d_in[3];
  const float* wo  = (const float*)d_in[4];
  const float* w1  = (const float*)d_in[5];
  const float* b1  = (const float*)d_in[6];
  const float* w2  = (const float*)d_in[7];
  const float* b2  = (const float*)d_in[8];
  const float* g1  = (const float*)d_in[9];
  const float* be1 = (const float*)d_in[10];
  const float* g2  = (const float*)d_in[11];
  const float* be2 = (const float*)d_in[12];
  float* out = (float*)d_out;

  char* ws = (char*)d_ws;
  bf16u* wqkv_t = (bf16u*)(ws);              //  0 ..  6 MB  (3072 x 1024)
  bf16u* wo_t   = (bf16u*)(ws +  6291456);   //  6 ..  8 MB  (1024 x 1024)
  bf16u* w1_t   = (bf16u*)(ws +  8388608);   //  8 .. 16 MB  (4096 x 1024)
  bf16u* w2_t   = (bf16u*)(ws + 16777216);   // 16 .. 24 MB  (1024 x 4096)
  bf16u* lnbuf  = (bf16u*)(ws + 25165824);   // 24 .. 32 MB  (4096 x 1024) also attn out
  bf16u* qkv    = (bf16u*)(ws + 33554432);   // 32 .. 56 MB  (4096 x 3072)
  bf16u* vtb    = (bf16u*)(ws + 58720256);   // 56 .. 64 MB  (32 x 64 x 2048)
  bf16u* h1     = (bf16u*)(ws + 33554432);   // 32 .. 64 MB  (reuse: 4096 x 4096)
  bf16u* attn   = lnbuf;                     // ln1 dead after QKV GEMM

  const dim3 tb32(32, 8);
  wtrans4<<<dim3(32, 32, 4), tb32, 0, stream>>>(wq, wk, wvv, wo, wqkv_t);
  wtrans<<<dim3(128, 32), tb32, 0, stream>>>(w1, w1_t, 1024, 4096);
  wtrans<<<dim3(32, 128), tb32, 0, stream>>>(w2, w2_t, 4096, 1024);

  ln_kernel<<<4096, 256, 0, stream>>>(x, g1, be1, lnbuf);
  gemm_bt<<<dim3(24, 32), 256, 0, stream>>>(lnbuf, wqkv_t, 4096, 3072, 1024,
                                            nullptr, nullptr, qkv, nullptr, 0);
  vtrans<<<dim3(64, 2, 32), tb32, 0, stream>>>(qkv, vtb);
  attn_kernel<<<dim3(32, 32), 256, 0, stream>>>(qkv, vtb, attn);
  gemm_bt64<<<dim3(8, 64), 256, 0, stream>>>(attn, wo_t, 4096, 1024, 1024,
                                             nullptr, x, nullptr, out, 2);
  ln_kernel<<<4096, 256, 0, stream>>>(out, g2, be2, lnbuf);
  gemm_bt<<<dim3(32, 32), 256, 0, stream>>>(lnbuf, w1_t, 4096, 4096, 1024,
                                            b1, nullptr, h1, nullptr, 1);
  gemm_bt64<<<dim3(8, 64), 256, 0, stream>>>(h1, w2_t, 4096, 1024, 4096,
                                             b2, out, nullptr, out, 3);
}